// Round 5
// baseline (179.144 us; speedup 1.0000x reference)
//
#include <hip/hip_runtime.h>
#include <math.h>

#define LN_EPS 1e-5f

constexpr int D = 1024;
constexpr int S = 4096;
constexpr int B = 4;
constexpr int KH = 512;                 // Hermitian-packed spectral columns
constexpr float NEG_TWO_PI = -6.283185307179586f;
constexpr float RSQ2 = 0.70710678118654752f;

__device__ __forceinline__ float2 cmul(float2 a, float2 b) {
    return make_float2(a.x * b.x - a.y * b.y, a.x * b.y + a.y * b.x);
}
__device__ __forceinline__ float2 csq(float2 a) {
    return make_float2(a.x * a.x - a.y * a.y, 2.f * a.x * a.y);
}
__device__ __forceinline__ float2 cadd(float2 a, float2 b) { return make_float2(a.x + b.x, a.y + b.y); }
__device__ __forceinline__ float2 csub(float2 a, float2 b) { return make_float2(a.x - b.x, a.y - b.y); }
__device__ __forceinline__ float2 cnegi(float2 a) { return make_float2(a.y, -a.x); }   // -i*a
__device__ __forceinline__ float2 cposi(float2 a) { return make_float2(-a.y, a.x); }   // +i*a

// Padded LDS index for the 1024-entry float2 array: conflict-free b64 access
// at every radix-4 stage stride (1,4,16,64,256).
__device__ __forceinline__ int P(int a) { return a + (a >> 4); }

// base-4 digit reversal of a 10-bit index
__device__ __forceinline__ int rev4_10(int v) {
    unsigned br = __brev((unsigned)v) >> 22;
    return (int)(((br & 0x155u) << 1) | ((br & 0x2AAu) >> 1));
}

// 8-point DFT, in place on 8 complex registers (W_8 constants inline).
__device__ __forceinline__ void dft8(float2& c0, float2& c1, float2& c2, float2& c3,
                                     float2& c4, float2& c5, float2& c6, float2& c7) {
    float2 t0 = cadd(c0, c4), t1 = csub(c0, c4);
    float2 t2 = cadd(c2, c6), t3 = csub(c2, c6);
    float2 t4 = cadd(c1, c5), t5 = csub(c1, c5);
    float2 t6 = cadd(c3, c7), t7 = csub(c3, c7);
    float2 E0 = cadd(t0, t2), E2 = csub(t0, t2);
    float2 E1 = cadd(t1, cnegi(t3)), E3 = cadd(t1, cposi(t3));
    float2 O0 = cadd(t4, t6), O2 = csub(t4, t6);
    float2 O1 = cadd(t5, cnegi(t7)), O3 = cadd(t5, cposi(t7));
    float2 W1O1 = make_float2(RSQ2 * (O1.x + O1.y), RSQ2 * (O1.y - O1.x));   // W8^1*O1
    float2 W2O2 = cnegi(O2);                                                  // W8^2*O2
    float2 W3O3 = make_float2(RSQ2 * (O3.y - O3.x), -RSQ2 * (O3.x + O3.y)); // W8^3*O3
    c0 = cadd(E0, O0); c4 = csub(E0, O0);
    c1 = cadd(E1, W1O1); c5 = csub(E1, W1O1);
    c2 = cadd(E2, W2O2); c6 = csub(E2, W2O2);
    c3 = cadd(E3, W3O3); c7 = csub(E3, W3O3);
}

// Two radix-8 stages over the 64 rows of a 64x64 float2 tile (rows assumed
// loaded in octal-digit-reversed order); natural-order rows on exit.
// 256 threads; all LDS access is row-fixed/col=lane -> conflict-free.
__device__ __forceinline__ void fft64_rows(float2* tile, const float2* tw64) {
#pragma unroll
    for (int h = 0; h < 2; ++h) {        // stage 0: groups of 8 consecutive rows
        int bf = threadIdx.x + (h << 8);
        int col = bf & 63;
        int g = bf >> 6;
#define R0(mm) tile[((((g) << 3) | (mm)) << 6) | col]
        float2 c0 = R0(0), c1 = R0(1), c2 = R0(2), c3 = R0(3);
        float2 c4 = R0(4), c5 = R0(5), c6 = R0(6), c7 = R0(7);
        dft8(c0, c1, c2, c3, c4, c5, c6, c7);
        R0(0) = c0; R0(1) = c1; R0(2) = c2; R0(3) = c3;
        R0(4) = c4; R0(5) = c5; R0(6) = c6; R0(7) = c7;
#undef R0
    }
    __syncthreads();
#pragma unroll
    for (int h = 0; h < 2; ++h) {        // stage 1: rows j+8m, twiddle W_64^{j*m}
        int bf = threadIdx.x + (h << 8);
        int col = bf & 63;
        int j = bf >> 6;
#define R1(mm) tile[(((j) + ((mm) << 3)) << 6) | col]
        float2 c0 = R1(0);
        float2 c1 = cmul(R1(1), tw64[j]);
        float2 c2 = cmul(R1(2), tw64[2 * j]);
        float2 c3 = cmul(R1(3), tw64[3 * j]);
        float2 c4 = cmul(R1(4), tw64[4 * j]);
        float2 c5 = cmul(R1(5), tw64[5 * j]);
        float2 c6 = cmul(R1(6), tw64[6 * j]);
        float2 c7 = cmul(R1(7), tw64[7 * j]);
        dft8(c0, c1, c2, c3, c4, c5, c6, c7);
        R1(0) = c0; R1(1) = c1; R1(2) = c2; R1(3) = c3;
        R1(4) = c4; R1(5) = c5; R1(6) = c6; R1(7) = c7;
#undef R1
    }
    __syncthreads();
}

// ---------------------------------------------------------------------------
// Kernel A: two rows per block. LN both rows, pack c = xn0 + i*xn1, radix-4
// DIF 1024-pt FFT (stage 0 in registers, fused with LN), untangle from the
// digit-reversed result, store Hermitian-half spectra.
// ---------------------------------------------------------------------------
__global__ __launch_bounds__(256) void ln_fft_d(const float* __restrict__ x,
                                                const float* __restrict__ gamma,
                                                const float* __restrict__ beta,
                                                float2* __restrict__ y) {
    __shared__ float2 cx[1088];          // 1024 + pad
    __shared__ float2 twA[256];          // W_1024^t
    __shared__ float red[36];

    const int tid = threadIdx.x;
    const size_t row0 = (size_t)blockIdx.x * 2;
    const float* x0 = x + row0 * D;
    const float* x1 = x0 + D;

    float wsn, wcs;
    __sincosf(NEG_TWO_PI * (float)tid * (1.0f / 1024.0f), &wsn, &wcs);
    const float2 w1s0 = make_float2(wcs, wsn);
    twA[tid] = w1s0;

    // ---- strided loads (coalesced dwords) + LN statistics ----
    float a0[4], a1[4];
    float s0 = 0.f, q0 = 0.f, s1 = 0.f, q1 = 0.f;
#pragma unroll
    for (int j = 0; j < 4; ++j) {
        float u = x0[tid + (j << 8)];
        float v = x1[tid + (j << 8)];
        a0[j] = u; a1[j] = v;
        s0 += u; q0 += u * u; s1 += v; q1 += v * v;
    }
#pragma unroll
    for (int off = 32; off; off >>= 1) {
        s0 += __shfl_down(s0, off); q0 += __shfl_down(q0, off);
        s1 += __shfl_down(s1, off); q1 += __shfl_down(q1, off);
    }
    const int wid = tid >> 6;
    if ((tid & 63) == 0) { red[wid] = s0; red[8 + wid] = q0; red[16 + wid] = s1; red[24 + wid] = q1; }
    __syncthreads();
    if (tid == 0) {
        float S0 = red[0] + red[1] + red[2] + red[3];
        float Q0 = red[8] + red[9] + red[10] + red[11];
        float S1 = red[16] + red[17] + red[18] + red[19];
        float Q1 = red[24] + red[25] + red[26] + red[27];
        float m0 = S0 * (1.0f / D), m1 = S1 * (1.0f / D);
        red[32] = m0; red[33] = rsqrtf(Q0 * (1.0f / D) - m0 * m0 + LN_EPS);
        red[34] = m1; red[35] = rsqrtf(Q1 * (1.0f / D) - m1 * m1 + LN_EPS);
    }
    __syncthreads();
    const float m0 = red[32], r0 = red[33], m1 = red[34], r1 = red[35];

    // ---- normalize (both rows packed) + stage-0 radix-4 DIF in registers ----
    float2 A0, A1, A2, A3;
    {
        float gg, bb;
        gg = gamma[tid];       bb = beta[tid];
        A0 = make_float2((a0[0] - m0) * r0 * gg + bb, (a1[0] - m1) * r1 * gg + bb);
        gg = gamma[tid + 256]; bb = beta[tid + 256];
        A1 = make_float2((a0[1] - m0) * r0 * gg + bb, (a1[1] - m1) * r1 * gg + bb);
        gg = gamma[tid + 512]; bb = beta[tid + 512];
        A2 = make_float2((a0[2] - m0) * r0 * gg + bb, (a1[2] - m1) * r1 * gg + bb);
        gg = gamma[tid + 768]; bb = beta[tid + 768];
        A3 = make_float2((a0[3] - m0) * r0 * gg + bb, (a1[3] - m1) * r1 * gg + bb);
    }
    {
        float2 b0 = cadd(A0, A2), b1 = csub(A0, A2);
        float2 b2 = cadd(A1, A3), b3 = csub(A1, A3);
        float2 w2 = csq(w1s0), w3 = cmul(w1s0, w2);
        cx[P(tid)]       = cadd(b0, b2);
        cx[P(tid + 256)] = cmul(cadd(b1, cnegi(b3)), w1s0);
        cx[P(tid + 512)] = cmul(csub(b0, b2), w2);
        cx[P(tid + 768)] = cmul(cadd(b1, cposi(b3)), w3);
    }
    __syncthreads();

    // ---- DIF stages L = 256, 64, 16 ----
#pragma unroll
    for (int sIdx = 0; sIdx < 3; ++sIdx) {
        const int lL = 8 - 2 * sIdx;          // log2 L
        const int qq = 1 << (lL - 2);         // L/4
        const int j = tid & (qq - 1);
        const int base = ((tid >> (lL - 2)) << lL) | j;
        const float2 w1 = twA[j << (10 - lL)];
        const float2 w2 = csq(w1), w3 = cmul(w1, w2);
        const int p0 = P(base), p1 = P(base + qq), p2 = P(base + 2 * qq), p3 = P(base + 3 * qq);
        float2 B0 = cx[p0], B1 = cx[p1], B2 = cx[p2], B3 = cx[p3];
        float2 b0 = cadd(B0, B2), b1 = csub(B0, B2);
        float2 b2 = cadd(B1, B3), b3 = csub(B1, B3);
        cx[p0] = cadd(b0, b2);
        cx[p1] = cmul(cadd(b1, cnegi(b3)), w1);
        cx[p2] = cmul(csub(b0, b2), w2);
        cx[p3] = cmul(cadd(b1, cposi(b3)), w3);
        __syncthreads();
    }
    // ---- final stage L = 4 (all twiddles = 1) ----
    {
        const int base = tid << 2;
        const int p0 = P(base), p1 = P(base + 1), p2 = P(base + 2), p3 = P(base + 3);
        float2 B0 = cx[p0], B1 = cx[p1], B2 = cx[p2], B3 = cx[p3];
        float2 b0 = cadd(B0, B2), b1 = csub(B0, B2);
        float2 b2 = cadd(B1, B3), b3 = csub(B1, B3);
        cx[p0] = cadd(b0, b2);
        cx[p1] = cadd(b1, cnegi(b3));
        cx[p2] = csub(b0, b2);
        cx[p3] = cadd(b1, cposi(b3));
    }
    __syncthreads();

    // ---- untangle (result at position p is X[rev4(p)]) ----
    float2* y0 = y + row0 * KH;
    float2* y1 = y0 + KH;
    if (tid == 0) {
        float2 X0 = cx[P(0)];
        float2 X512 = cx[P(2)];              // rev4(512) = 2
        y0[0] = make_float2(X0.x, X512.x);   // (Y0[0], Y0[512]) both real
        y1[0] = make_float2(X0.y, X512.y);
    } else {
        int kc = tid;
        float2 XA = cx[P(rev4_10(kc))];
        float2 XB = cx[P(rev4_10(1024 - kc))];
        y0[kc] = make_float2(0.5f * (XA.x + XB.x), 0.5f * (XA.y - XB.y));
        y1[kc] = make_float2(0.5f * (XA.y + XB.y), 0.5f * (XB.x - XA.x));
    }
    {
        int kc = tid + 256;
        float2 XA = cx[P(rev4_10(kc))];
        float2 XB = cx[P(rev4_10(1024 - kc))];
        y0[kc] = make_float2(0.5f * (XA.x + XB.x), 0.5f * (XA.y - XB.y));
        y1[kc] = make_float2(0.5f * (XA.y + XB.y), 0.5f * (XB.x - XA.x));
    }
}

// ---------------------------------------------------------------------------
// Four-step FFT over S = 4096 = 64 x 64 on the 512 packed columns (radix-8).
// Pass 1 (in place): fixed n1: FFT64 over n2, twiddle W_4096^{n1*k2} via a
// chained rotation, store Z[b][k2][n1][kc].
// ---------------------------------------------------------------------------
__global__ __launch_bounds__(256) void fft_s_p1(const float2* y, float2* z) {
    __shared__ float2 tile[64 * 64];     // [row][col], col = lane: conflict-free
    __shared__ float2 tw64[64];          // W_64^t

    const int bid = blockIdx.x;
    const int dt = bid & 7;
    const int n1 = (bid >> 3) & 63;
    const int b  = bid >> 9;
    const int d0 = dt << 6;
    const int lane = threadIdx.x & 63;
    const int r4   = threadIdx.x >> 6;

    if (threadIdx.x < 64) {
        float sn, c;
        __sincosf(NEG_TWO_PI * (float)threadIdx.x * (1.0f / 64.0f), &sn, &c);
        tw64[threadIdx.x] = make_float2(c, sn);
    }

    // gather rows s = n1 + 64*n2, octal-digit-reversed row placement
#pragma unroll
    for (int m = 0; m < 16; ++m) {
        int n2 = (m << 2) | r4;
        int rr = ((n2 & 7) << 3) | (n2 >> 3);
        tile[(rr << 6) | lane] =
            y[(size_t)((b << 12) | (n2 << 6) | n1) * KH + d0 + lane];
    }
    __syncthreads();

    fft64_rows(tile, tw64);

    // twiddle by W_4096^{n1*k2} (chained rotation), store Z[b][k2][n1][kc]
    float2 wq, wstep;
    {
        float sn, c;
        __sincosf(NEG_TWO_PI * (float)(n1 * r4) * (1.0f / 4096.0f), &sn, &c);
        wq = make_float2(c, sn);
        __sincosf(NEG_TWO_PI * (float)n1 * (1.0f / 1024.0f), &sn, &c);
        wstep = make_float2(c, sn);      // W_4096^{4*n1}
    }
#pragma unroll
    for (int m = 0; m < 16; ++m) {
        int k2 = (m << 2) | r4;
        float2 vv = tile[(k2 << 6) | lane];
        z[(size_t)((b << 12) | (k2 << 6) | n1) * KH + d0 + lane] = cmul(vv, wq);
        wq = cmul(wq, wstep);
    }
}

// ---------------------------------------------------------------------------
// Pass 2 + fused packed-column completion (radix-8).
// ---------------------------------------------------------------------------
__global__ __launch_bounds__(256) void fft_s_p2(const float2* __restrict__ z,
                                                float* __restrict__ out) {
    __shared__ float2 tile[64 * 64];
    __shared__ float2 tw64[64];

    const int lane = threadIdx.x & 63;
    const int r4   = threadIdx.x >> 6;

    if (threadIdx.x < 64) {
        float sn, c;
        __sincosf(NEG_TWO_PI * (float)threadIdx.x * (1.0f / 64.0f), &sn, &c);
        tw64[threadIdx.x] = make_float2(c, sn);
    }

    if (blockIdx.x < B * 64 * 8) {
        const int bid = blockIdx.x;
        const int dt = bid & 7;
        const int k2 = (bid >> 3) & 63;
        const int b  = bid >> 9;
        const int d0 = dt << 6;

#pragma unroll
        for (int m = 0; m < 16; ++m) {
            int n1 = (m << 2) | r4;
            int rr = ((n1 & 7) << 3) | (n1 >> 3);
            tile[(rr << 6) | lane] =
                z[(size_t)((b << 12) | (k2 << 6) | n1) * KH + d0 + lane];
        }
        __syncthreads();

        fft64_rows(tile, tw64);

        const int kc = d0 + lane;
#pragma unroll
        for (int m = 0; m < 16; ++m) {
            int k1 = (m << 2) | r4;
            int q = (k1 << 6) | k2;
            float v = tile[(k1 << 6) | lane].x;
            if (kc) {
                out[((size_t)(b << 12) + (size_t)q) * D + kc] = v;
                int qm = (S - q) & (S - 1);
                out[((size_t)(b << 12) + (size_t)qm) * D + (D - kc)] = v;
            }
        }
    } else {
        // ---- packed-column (k=0 & k=512) completion for batch b ----
        const int b = blockIdx.x - B * 64 * 8;

#pragma unroll
        for (int m = 0; m < 16; ++m) {
            int k2 = (m << 2) | r4;
            int rr = ((lane & 7) << 3) | (lane >> 3);   // lane = n1
            tile[(rr << 6) | k2] = z[(size_t)((b << 12) | (k2 << 6) | lane) * KH];
        }
        __syncthreads();

        fft64_rows(tile, tw64);

        // tile[k1][k2] = H[q], q = k2+64*k1, H = G_0 + i*G_512
#pragma unroll
        for (int m = 0; m < 16; ++m) {
            int k1 = (m << 2) | r4;
            int k2 = lane;
            int q = (k1 << 6) | k2;
            int k2m = (64 - k2) & 63;
            int k1m = (k2 == 0) ? ((64 - k1) & 63) : (63 - k1);
            float2 Hq = tile[(k1 << 6) | k2];
            float2 Hm = tile[(k1m << 6) | k2m];
            size_t ob = ((size_t)(b << 12) + (size_t)q) * D;
            out[ob]       = 0.5f * (Hq.x + Hm.x);
            out[ob + 512] = 0.5f * (Hq.y + Hm.y);
        }
    }
}

extern "C" void kernel_launch(void* const* d_in, const int* in_sizes, int n_in,
                              void* d_out, int out_size, void* d_ws, size_t ws_size,
                              hipStream_t stream) {
    const float* x     = (const float*)d_in[0];
    const float* gamma = (const float*)d_in[1];
    const float* beta  = (const float*)d_in[2];
    float* out = (float*)d_out;

    float2* y = (float2*)d_ws;   // 64 MB Hermitian-packed spectra; p1 in place

    ln_fft_d<<<B * S / 2, 256, 0, stream>>>(x, gamma, beta, y);
    fft_s_p1<<<B * 64 * 8, 256, 0, stream>>>(y, y);
    fft_s_p2<<<B * 64 * 8 + B, 256, 0, stream>>>(y, out);
}